// Round 2
// baseline (118.957 us; speedup 1.0000x reference)
//
#include <hip/hip_runtime.h>
#include <math.h>

// Grid 2048 x 256. Each block = 4 independent waves; each wave processes 2
// consecutive 32x32 images (16 px/thread). ALL 8 input loads (both images)
// are issued nontemporally at wave entry, before LDS setup, so the full
// 128 B/lane is in flight during setup. No __syncthreads: waves use disjoint
// LDS slices; LDS pipe is in-order within a wave;
// __builtin_amdgcn_wave_barrier() fences the compiler.
//
// FAST PATH (taken when all 8 neighbor weights are equal — true for the
// Laplacian input): conv = k0*sum9 + (k4-k0)*x, sum9 via separable rowsums.
//  - horizontal rowsums in registers; left/right neighbor pixels come from
//    zero-fill wave-DPP shifts (no raw-pixel LDS, no column borders);
//  - rowsums staged to LDS (4 ds_write_b128), vertical sum = 2 ds_read_b128
//    per chunk (top/bottom) + own rowsum from registers.
// Generic fallback: raw 9-fma conv via LDS tile.
// LDS slice/wave: 34 rows x stride 36 + pad = 1228 floats; data at col+4
// (16B-aligned b128); rows 0/33 zeroed (vertical padding), cols 0,3 zeroed
// for the generic path's halo.
//
// Streaming hygiene: input is read-once, output write-once -> both use
// nontemporal (nt) accesses to avoid L2 thrash between the two streams.
// NOTE: __builtin_nontemporal_load/store require clang ext_vector_type
// pointers — HIP's float4 struct is NOT accepted (round-1 compile fail).

#define S 36
#define SLICE 1228

typedef float floatx4 __attribute__((ext_vector_type(4)));

__device__ __forceinline__ float4 ntload4(const float* p) {
    floatx4 v = __builtin_nontemporal_load((const floatx4*)p);
    return make_float4(v.x, v.y, v.z, v.w);
}

template <int CTRL>
__device__ __forceinline__ float dppmov(float x) {
    // old = src => bound lanes keep x (identity for min/max)
    return __int_as_float(__builtin_amdgcn_update_dpp(
        __float_as_int(x), __float_as_int(x), CTRL, 0xf, 0xf, false));
}

template <int CTRL>
__device__ __forceinline__ float dppsh0(float x) {
    // zero-fill shift: old = 0, bound_ctrl = true
    return __int_as_float(__builtin_amdgcn_update_dpp(
        0, __float_as_int(x), CTRL, 0xf, 0xf, true));
}

__device__ __forceinline__ void wave64_minmax(float& mn, float& mx) {
    mn = fminf(mn, dppmov<0x111>(mn)); mx = fmaxf(mx, dppmov<0x111>(mx)); // row_shr:1
    mn = fminf(mn, dppmov<0x112>(mn)); mx = fmaxf(mx, dppmov<0x112>(mx)); // row_shr:2
    mn = fminf(mn, dppmov<0x114>(mn)); mx = fmaxf(mx, dppmov<0x114>(mx)); // row_shr:4
    mn = fminf(mn, dppmov<0x118>(mn)); mx = fmaxf(mx, dppmov<0x118>(mx)); // row_shr:8
    mn = fminf(mn, dppmov<0x142>(mn)); mx = fmaxf(mx, dppmov<0x142>(mx)); // row_bcast:15
    mn = fminf(mn, dppmov<0x143>(mn)); mx = fmaxf(mx, dppmov<0x143>(mx)); // row_bcast:31
    // lane 63 holds the wave-wide min / max
}

// Reductions + normalize + clip + floor + store (shared by both paths).
__device__ __forceinline__ void finish_image(
    const float4* __restrict__ x4, float conv[4][4],
    float* __restrict__ dst, int lane)
{
    // ---- reduction 1: min/max of conv ----
    float mn = conv[0][0], mx = conv[0][0];
#pragma unroll
    for (int i = 0; i < 4; ++i)
#pragma unroll
        for (int j = 0; j < 4; ++j) {
            mn = fminf(mn, conv[i][j]);
            mx = fmaxf(mx, conv[i][j]);
        }
    wave64_minmax(mn, mx);
    const float cmin = __int_as_float(__builtin_amdgcn_readlane(__float_as_int(mn), 63));
    const float cmax = __int_as_float(__builtin_amdgcn_readlane(__float_as_int(mx), 63));

    const float inv1 = 255.0f / fmaxf(cmax - cmin, 1e-6f);
    float sh[4][4];
#pragma unroll
    for (int i = 0; i < 4; ++i) {
        sh[i][0] = x4[i].x + (conv[i][0] - cmin) * inv1;
        sh[i][1] = x4[i].y + (conv[i][1] - cmin) * inv1;
        sh[i][2] = x4[i].z + (conv[i][2] - cmin) * inv1;
        sh[i][3] = x4[i].w + (conv[i][3] - cmin) * inv1;
    }

    // ---- reduction 2: min/max of sharpened ----
    mn = sh[0][0]; mx = sh[0][0];
#pragma unroll
    for (int i = 0; i < 4; ++i)
#pragma unroll
        for (int j = 0; j < 4; ++j) {
            mn = fminf(mn, sh[i][j]);
            mx = fmaxf(mx, sh[i][j]);
        }
    wave64_minmax(mn, mx);
    const float smin = __int_as_float(__builtin_amdgcn_readlane(__float_as_int(mn), 63));
    const float smax = __int_as_float(__builtin_amdgcn_readlane(__float_as_int(mx), 63));

    // res = floor(clip(sh*inv2 + c2, 0, 255)),  c2 = -smin*inv2 (uniform)
    const float inv2 = 255.0f / fminf(fmaxf(smax - smin, 1e-6f), 255.0f);
    const float c2 = -smin * inv2;
#pragma unroll
    for (int i = 0; i < 4; ++i) {
        floatx4 o;
        o.x = floorf(fminf(fmaxf(sh[i][0] * inv2 + c2, 0.0f), 255.0f));
        o.y = floorf(fminf(fmaxf(sh[i][1] * inv2 + c2, 0.0f), 255.0f));
        o.z = floorf(fminf(fmaxf(sh[i][2] * inv2 + c2, 0.0f), 255.0f));
        o.w = floorf(fminf(fmaxf(sh[i][3] * inv2 + c2, 0.0f), 255.0f));
        __builtin_nontemporal_store(o, (floatx4*)(dst + i * 256 + lane * 4));
    }
}

// Fast path: all 8 neighbor coefficients equal k0, center k4.
__device__ __forceinline__ void process_image_fast(
    float* __restrict__ sm, const float4* __restrict__ x4,
    float k0, float dk, float* __restrict__ dst, int lane)
{
    const int rbase = lane >> 3;        // 0..7
    const int col0  = (lane & 7) << 2;  // 0,4,...,28
    const bool ledge = (lane & 7) == 0;
    const bool redge = (lane & 7) == 7;

    float4 rs[4];  // horizontal rowsums of own rows
    __builtin_amdgcn_wave_barrier();
#pragma unroll
    for (int i = 0; i < 4; ++i) {
        const float4 m = x4[i];
        float lv = dppsh0<0x138>(m.w);  // wave_shr:1 -> lane-1's m.w
        float rv = dppsh0<0x130>(m.x);  // wave_shl:1 -> lane+1's m.x
        lv = ledge ? 0.0f : lv;
        rv = redge ? 0.0f : rv;
        const float t1 = m.x + m.y;
        const float t2 = m.z + m.w;
        rs[i].x = lv + t1;
        rs[i].y = t1 + m.z;
        rs[i].z = m.y + t2;
        rs[i].w = t2 + rv;
        *(float4*)&sm[(i * 8 + rbase + 1) * S + (col0 + 4)] = rs[i];
    }
    __builtin_amdgcn_wave_barrier();

    float conv[4][4];
#pragma unroll
    for (int i = 0; i < 4; ++i) {
        const int row = i * 8 + rbase;  // image row
        const float4 top = *(const float4*)&sm[ row      * S + col0 + 4];
        const float4 bot = *(const float4*)&sm[(row + 2) * S + col0 + 4];
        conv[i][0] = (top.x + rs[i].x + bot.x) * k0 + dk * x4[i].x;
        conv[i][1] = (top.y + rs[i].y + bot.y) * k0 + dk * x4[i].y;
        conv[i][2] = (top.z + rs[i].z + bot.z) * k0 + dk * x4[i].z;
        conv[i][3] = (top.w + rs[i].w + bot.w) * k0 + dk * x4[i].w;
    }
    __builtin_amdgcn_wave_barrier();

    finish_image(x4, conv, dst, lane);
}

// Generic fallback: raw pixels in LDS, 9-fma conv.
__device__ __forceinline__ void process_image_gen(
    float* __restrict__ sm, const float4* __restrict__ x4, const float* k,
    float* __restrict__ dst, int lane)
{
    const int rbase = lane >> 3;
    const int col0  = (lane & 7) << 2;

    __builtin_amdgcn_wave_barrier();
#pragma unroll
    for (int i = 0; i < 4; ++i)
        *(float4*)&sm[(i * 8 + rbase + 1) * S + (col0 + 4)] = x4[i];
    __builtin_amdgcn_wave_barrier();

    float conv[4][4];
#pragma unroll
    for (int i = 0; i < 4; ++i) {
        const int row = i * 8 + rbase;
        const float* pt = &sm[ row      * S + col0];
        const float* pm = &sm[(row + 1) * S + col0];
        const float* pb = &sm[(row + 2) * S + col0];
        const float  tl = pt[3], tr = pt[8];
        const float4 tm = *(const float4*)(pt + 4);
        const float  ml = pm[3], mr = pm[8];
        const float  bl = pb[3], br = pb[8];
        const float4 bm = *(const float4*)(pb + 4);
        const float4 m  = x4[i];
        conv[i][0] = k[0]*tl   + k[1]*tm.x + k[2]*tm.y
                   + k[3]*ml   + k[4]*m.x  + k[5]*m.y
                   + k[6]*bl   + k[7]*bm.x + k[8]*bm.y;
        conv[i][1] = k[0]*tm.x + k[1]*tm.y + k[2]*tm.z
                   + k[3]*m.x  + k[4]*m.y  + k[5]*m.z
                   + k[6]*bm.x + k[7]*bm.y + k[8]*bm.z;
        conv[i][2] = k[0]*tm.y + k[1]*tm.z + k[2]*tm.w
                   + k[3]*m.y  + k[4]*m.z  + k[5]*m.w
                   + k[6]*bm.y + k[7]*bm.z + k[8]*bm.w;
        conv[i][3] = k[0]*tm.z + k[1]*tm.w + k[2]*tr
                   + k[3]*m.z  + k[4]*m.w  + k[5]*mr
                   + k[6]*bm.z + k[7]*bm.w + k[8]*br;
    }
    __builtin_amdgcn_wave_barrier();

    finish_image(x4, conv, dst, lane);
}

__global__ __launch_bounds__(256) void laplacian_fwd_kernel(
    const float* __restrict__ in,      // (16384, 1, 32, 32)
    const float* __restrict__ weight,  // (1, 9)
    const float* __restrict__ wfac,    // (1, 1)
    float* __restrict__ out)           // (1, 16384, 1, 32, 32)
{
    __shared__ float lds[4 * SLICE];

    const int t    = threadIdx.x;
    const int w    = t >> 6;
    const int lane = t & 63;
    float* sm = &lds[w * SLICE];

    const int W = blockIdx.x * 4 + w;            // 0..8191
    const size_t base0 = (size_t)(2 * W) * 1024;
    const size_t base1 = base0 + 1024;

    // Issue ALL vmem loads (both images, nontemporal) before any setup, so
    // the full 128 B/lane is in flight during LDS zeroing + weight loads.
    float4 xa[4], xb[4];
#pragma unroll
    for (int i = 0; i < 4; ++i)
        xa[i] = ntload4(in + base0 + i * 256 + lane * 4);
#pragma unroll
    for (int i = 0; i < 4; ++i)
        xb[i] = ntload4(in + base1 + i * 256 + lane * 4);

    // Border zeros (persist for both images / both paths):
    // rows 0,33 full width; generic-path column halos at cols 0,3; pad.
    if (lane < 36) { sm[lane] = 0.0f; sm[33 * S + lane] = 0.0f; }
    if (lane < 32) { sm[(lane + 1) * S] = 0.0f; sm[(lane + 1) * S + 3] = 0.0f; }
    if (lane == 0) sm[34 * S] = 0.0f;

    // Kernel coefficients (uniform).
    const float wf = fminf(fmaxf(wfac[0], 1.001f), 254.999f);
    float k[9];
#pragma unroll
    for (int i = 0; i < 9; ++i)
        k[i] = fminf(fmaxf(weight[i], -0.999f), 0.999f) * wf;

    // Wave-uniform specialization: all 8 neighbor coefficients equal?
    const bool fast = (k[0] == k[1]) && (k[0] == k[2]) && (k[0] == k[3]) &&
                      (k[0] == k[5]) && (k[0] == k[6]) && (k[0] == k[7]) &&
                      (k[0] == k[8]);
    if (fast) {
        const float dk = k[4] - k[0];
        process_image_fast(sm, xa, k[0], dk, out + base0, lane);
        process_image_fast(sm, xb, k[0], dk, out + base1, lane);
    } else {
        process_image_gen(sm, xa, k, out + base0, lane);
        process_image_gen(sm, xb, k, out + base1, lane);
    }
}

extern "C" void kernel_launch(void* const* d_in, const int* in_sizes, int n_in,
                              void* d_out, int out_size, void* d_ws, size_t ws_size,
                              hipStream_t stream) {
    const float* in   = (const float*)d_in[0];  // (16384,1,32,32)
    const float* w    = (const float*)d_in[1];  // (1,9)
    const float* wfac = (const float*)d_in[2];  // (1,1)
    float* out = (float*)d_out;                 // (1,16384,1,32,32)
    const int B = in_sizes[0] / 1024;           // 16384
    const int nblocks = B / 8;                  // 4 waves x 2 images each
    laplacian_fwd_kernel<<<nblocks, 256, 0, stream>>>(in, w, wfac, out);
}

// Round 3
// 111.015 us; speedup vs baseline: 1.0715x; 1.0715x over previous
//
#include <hip/hip_runtime.h>
#include <math.h>

// Grid 2048 x 256. Each block = 4 independent waves; each wave processes 2
// consecutive 32x32 images (16 px/thread), image-1 loads prefetched before
// image-0 compute. No __syncthreads: waves use disjoint LDS slices; LDS pipe
// is in-order within a wave; __builtin_amdgcn_wave_barrier() fences the
// compiler.
//
// R1 lesson (measured): nontemporal INPUT loads regress 110.8 -> 119.0 us.
// The 64 MB input is L2/L3-resident across graph iterations; default cached
// loads win. Output stores stay nontemporal (write-once, never re-read).
//
// FAST PATH (taken when all 8 neighbor weights are equal — true for the
// Laplacian input): conv = k0*sum9 + (k4-k0)*x, sum9 via separable rowsums.
//  - horizontal rowsums in registers; left/right neighbor pixels come from
//    zero-fill wave-DPP shifts (no raw-pixel LDS, no column borders);
//  - rowsums staged to LDS (4 ds_write_b128), vertical sum = 2 ds_read_b128
//    per chunk (top/bottom) + own rowsum from registers.
// Generic fallback: raw 9-fma conv via LDS tile (R6 structure).
// LDS slice/wave: 34 rows x stride 36 + pad = 1228 floats; data at col+4
// (16B-aligned b128); rows 0/33 zeroed (vertical padding), cols 0,3 zeroed
// for the generic path's halo.

#define S 36
#define SLICE 1228

typedef float floatx4 __attribute__((ext_vector_type(4)));

template <int CTRL>
__device__ __forceinline__ float dppmov(float x) {
    // old = src => bound lanes keep x (identity for min/max)
    return __int_as_float(__builtin_amdgcn_update_dpp(
        __float_as_int(x), __float_as_int(x), CTRL, 0xf, 0xf, false));
}

template <int CTRL>
__device__ __forceinline__ float dppsh0(float x) {
    // zero-fill shift: old = 0, bound_ctrl = true
    return __int_as_float(__builtin_amdgcn_update_dpp(
        0, __float_as_int(x), CTRL, 0xf, 0xf, true));
}

__device__ __forceinline__ void wave64_minmax(float& mn, float& mx) {
    mn = fminf(mn, dppmov<0x111>(mn)); mx = fmaxf(mx, dppmov<0x111>(mx)); // row_shr:1
    mn = fminf(mn, dppmov<0x112>(mn)); mx = fmaxf(mx, dppmov<0x112>(mx)); // row_shr:2
    mn = fminf(mn, dppmov<0x114>(mn)); mx = fmaxf(mx, dppmov<0x114>(mx)); // row_shr:4
    mn = fminf(mn, dppmov<0x118>(mn)); mx = fmaxf(mx, dppmov<0x118>(mx)); // row_shr:8
    mn = fminf(mn, dppmov<0x142>(mn)); mx = fmaxf(mx, dppmov<0x142>(mx)); // row_bcast:15
    mn = fminf(mn, dppmov<0x143>(mn)); mx = fmaxf(mx, dppmov<0x143>(mx)); // row_bcast:31
    // lane 63 holds the wave-wide min / max
}

// Reductions + normalize + clip + floor + store (shared by both paths).
__device__ __forceinline__ void finish_image(
    const float4* __restrict__ x4, float conv[4][4],
    float* __restrict__ dst, int lane)
{
    // ---- reduction 1: min/max of conv ----
    float mn = conv[0][0], mx = conv[0][0];
#pragma unroll
    for (int i = 0; i < 4; ++i)
#pragma unroll
        for (int j = 0; j < 4; ++j) {
            mn = fminf(mn, conv[i][j]);
            mx = fmaxf(mx, conv[i][j]);
        }
    wave64_minmax(mn, mx);
    const float cmin = __int_as_float(__builtin_amdgcn_readlane(__float_as_int(mn), 63));
    const float cmax = __int_as_float(__builtin_amdgcn_readlane(__float_as_int(mx), 63));

    const float inv1 = 255.0f / fmaxf(cmax - cmin, 1e-6f);
    float sh[4][4];
#pragma unroll
    for (int i = 0; i < 4; ++i) {
        sh[i][0] = x4[i].x + (conv[i][0] - cmin) * inv1;
        sh[i][1] = x4[i].y + (conv[i][1] - cmin) * inv1;
        sh[i][2] = x4[i].z + (conv[i][2] - cmin) * inv1;
        sh[i][3] = x4[i].w + (conv[i][3] - cmin) * inv1;
    }

    // ---- reduction 2: min/max of sharpened ----
    mn = sh[0][0]; mx = sh[0][0];
#pragma unroll
    for (int i = 0; i < 4; ++i)
#pragma unroll
        for (int j = 0; j < 4; ++j) {
            mn = fminf(mn, sh[i][j]);
            mx = fmaxf(mx, sh[i][j]);
        }
    wave64_minmax(mn, mx);
    const float smin = __int_as_float(__builtin_amdgcn_readlane(__float_as_int(mn), 63));
    const float smax = __int_as_float(__builtin_amdgcn_readlane(__float_as_int(mx), 63));

    // res = floor(clip(sh*inv2 + c2, 0, 255)),  c2 = -smin*inv2 (uniform)
    const float inv2 = 255.0f / fminf(fmaxf(smax - smin, 1e-6f), 255.0f);
    const float c2 = -smin * inv2;
#pragma unroll
    for (int i = 0; i < 4; ++i) {
        floatx4 o;
        o.x = floorf(fminf(fmaxf(sh[i][0] * inv2 + c2, 0.0f), 255.0f));
        o.y = floorf(fminf(fmaxf(sh[i][1] * inv2 + c2, 0.0f), 255.0f));
        o.z = floorf(fminf(fmaxf(sh[i][2] * inv2 + c2, 0.0f), 255.0f));
        o.w = floorf(fminf(fmaxf(sh[i][3] * inv2 + c2, 0.0f), 255.0f));
        __builtin_nontemporal_store(o, (floatx4*)(dst + i * 256 + lane * 4));
    }
}

// Fast path: all 8 neighbor coefficients equal k0, center k4.
__device__ __forceinline__ void process_image_fast(
    float* __restrict__ sm, const float4* __restrict__ x4,
    float k0, float dk, float* __restrict__ dst, int lane)
{
    const int rbase = lane >> 3;        // 0..7
    const int col0  = (lane & 7) << 2;  // 0,4,...,28
    const bool ledge = (lane & 7) == 0;
    const bool redge = (lane & 7) == 7;

    float4 rs[4];  // horizontal rowsums of own rows
    __builtin_amdgcn_wave_barrier();
#pragma unroll
    for (int i = 0; i < 4; ++i) {
        const float4 m = x4[i];
        float lv = dppsh0<0x138>(m.w);  // wave_shr:1 -> lane-1's m.w
        float rv = dppsh0<0x130>(m.x);  // wave_shl:1 -> lane+1's m.x
        lv = ledge ? 0.0f : lv;
        rv = redge ? 0.0f : rv;
        const float t1 = m.x + m.y;
        const float t2 = m.z + m.w;
        rs[i].x = lv + t1;
        rs[i].y = t1 + m.z;
        rs[i].z = m.y + t2;
        rs[i].w = t2 + rv;
        *(float4*)&sm[(i * 8 + rbase + 1) * S + (col0 + 4)] = rs[i];
    }
    __builtin_amdgcn_wave_barrier();

    float conv[4][4];
#pragma unroll
    for (int i = 0; i < 4; ++i) {
        const int row = i * 8 + rbase;  // image row
        const float4 top = *(const float4*)&sm[ row      * S + col0 + 4];
        const float4 bot = *(const float4*)&sm[(row + 2) * S + col0 + 4];
        conv[i][0] = (top.x + rs[i].x + bot.x) * k0 + dk * x4[i].x;
        conv[i][1] = (top.y + rs[i].y + bot.y) * k0 + dk * x4[i].y;
        conv[i][2] = (top.z + rs[i].z + bot.z) * k0 + dk * x4[i].z;
        conv[i][3] = (top.w + rs[i].w + bot.w) * k0 + dk * x4[i].w;
    }
    __builtin_amdgcn_wave_barrier();

    finish_image(x4, conv, dst, lane);
}

// Generic fallback: raw pixels in LDS, 9-fma conv (R6 structure).
__device__ __forceinline__ void process_image_gen(
    float* __restrict__ sm, const float4* __restrict__ x4, const float* k,
    float* __restrict__ dst, int lane)
{
    const int rbase = lane >> 3;
    const int col0  = (lane & 7) << 2;

    __builtin_amdgcn_wave_barrier();
#pragma unroll
    for (int i = 0; i < 4; ++i)
        *(float4*)&sm[(i * 8 + rbase + 1) * S + (col0 + 4)] = x4[i];
    __builtin_amdgcn_wave_barrier();

    float conv[4][4];
#pragma unroll
    for (int i = 0; i < 4; ++i) {
        const int row = i * 8 + rbase;
        const float* pt = &sm[ row      * S + col0];
        const float* pm = &sm[(row + 1) * S + col0];
        const float* pb = &sm[(row + 2) * S + col0];
        const float  tl = pt[3], tr = pt[8];
        const float4 tm = *(const float4*)(pt + 4);
        const float  ml = pm[3], mr = pm[8];
        const float  bl = pb[3], br = pb[8];
        const float4 bm = *(const float4*)(pb + 4);
        const float4 m  = x4[i];
        conv[i][0] = k[0]*tl   + k[1]*tm.x + k[2]*tm.y
                   + k[3]*ml   + k[4]*m.x  + k[5]*m.y
                   + k[6]*bl   + k[7]*bm.x + k[8]*bm.y;
        conv[i][1] = k[0]*tm.x + k[1]*tm.y + k[2]*tm.z
                   + k[3]*m.x  + k[4]*m.y  + k[5]*m.z
                   + k[6]*bm.x + k[7]*bm.y + k[8]*bm.z;
        conv[i][2] = k[0]*tm.y + k[1]*tm.z + k[2]*tm.w
                   + k[3]*m.y  + k[4]*m.z  + k[5]*m.w
                   + k[6]*bm.y + k[7]*bm.z + k[8]*bm.w;
        conv[i][3] = k[0]*tm.z + k[1]*tm.w + k[2]*tr
                   + k[3]*m.z  + k[4]*m.w  + k[5]*mr
                   + k[6]*bm.z + k[7]*bm.w + k[8]*br;
    }
    __builtin_amdgcn_wave_barrier();

    finish_image(x4, conv, dst, lane);
}

__global__ __launch_bounds__(256) void laplacian_fwd_kernel(
    const float* __restrict__ in,      // (16384, 1, 32, 32)
    const float* __restrict__ weight,  // (1, 9)
    const float* __restrict__ wfac,    // (1, 1)
    float* __restrict__ out)           // (1, 16384, 1, 32, 32)
{
    __shared__ float lds[4 * SLICE];

    const int t    = threadIdx.x;
    const int w    = t >> 6;
    const int lane = t & 63;
    float* sm = &lds[w * SLICE];

    const int W = blockIdx.x * 4 + w;            // 0..8191
    const size_t base0 = (size_t)(2 * W) * 1024;
    const size_t base1 = base0 + 1024;

    // Issue image-0 loads immediately.
    float4 xa[4];
#pragma unroll
    for (int i = 0; i < 4; ++i)
        xa[i] = *(const float4*)(in + base0 + i * 256 + lane * 4);

    // Border zeros (persist for both images / both paths):
    // rows 0,33 full width; generic-path column halos at cols 0,3; pad.
    if (lane < 36) { sm[lane] = 0.0f; sm[33 * S + lane] = 0.0f; }
    if (lane < 32) { sm[(lane + 1) * S] = 0.0f; sm[(lane + 1) * S + 3] = 0.0f; }
    if (lane == 0) sm[34 * S] = 0.0f;

    // Kernel coefficients (uniform).
    const float wf = fminf(fmaxf(wfac[0], 1.001f), 254.999f);
    float k[9];
#pragma unroll
    for (int i = 0; i < 9; ++i)
        k[i] = fminf(fmaxf(weight[i], -0.999f), 0.999f) * wf;

    // Prefetch image-1 loads before image-0 compute.
    float4 xb[4];
#pragma unroll
    for (int i = 0; i < 4; ++i)
        xb[i] = *(const float4*)(in + base1 + i * 256 + lane * 4);

    // Wave-uniform specialization: all 8 neighbor coefficients equal?
    const bool fast = (k[0] == k[1]) && (k[0] == k[2]) && (k[0] == k[3]) &&
                      (k[0] == k[5]) && (k[0] == k[6]) && (k[0] == k[7]) &&
                      (k[0] == k[8]);
    if (fast) {
        const float dk = k[4] - k[0];
        process_image_fast(sm, xa, k[0], dk, out + base0, lane);
        process_image_fast(sm, xb, k[0], dk, out + base1, lane);
    } else {
        process_image_gen(sm, xa, k, out + base0, lane);
        process_image_gen(sm, xb, k, out + base1, lane);
    }
}

extern "C" void kernel_launch(void* const* d_in, const int* in_sizes, int n_in,
                              void* d_out, int out_size, void* d_ws, size_t ws_size,
                              hipStream_t stream) {
    const float* in   = (const float*)d_in[0];  // (16384,1,32,32)
    const float* w    = (const float*)d_in[1];  // (1,9)
    const float* wfac = (const float*)d_in[2];  // (1,1)
    float* out = (float*)d_out;                 // (1,16384,1,32,32)
    const int B = in_sizes[0] / 1024;           // 16384
    const int nblocks = B / 8;                  // 4 waves x 2 images each
    laplacian_fwd_kernel<<<nblocks, 256, 0, stream>>>(in, w, wfac, out);
}